// Round 8
// baseline (297.342 us; speedup 1.0000x reference)
//
#include <hip/hip_runtime.h>

typedef unsigned short u16;
typedef unsigned int u32;
typedef unsigned short u16x8 __attribute__((ext_vector_type(8)));
typedef unsigned int u32x4 __attribute__((ext_vector_type(4)));
typedef __bf16 bf16x8 __attribute__((ext_vector_type(8)));
typedef float f32x4 __attribute__((ext_vector_type(4)));

#define QSCALE 0.18033688011112042f  /* 0.125 * log2(e) */

__device__ __forceinline__ u16 f2bf(float f) {
    unsigned u = __float_as_uint(f);
    u += 0x7fffu + ((u >> 16) & 1u);
    return (u16)(u >> 16);
}

// single-instruction packed f32x2 -> bf16x2 (RTNE), used in the attn hot loop
__device__ __forceinline__ u32 cvtpk(float lo, float hi) {
    u32 r;
    asm("v_cvt_pk_bf16_f32 %0, %1, %2" : "=v"(r) : "v"(lo), "v"(hi));
    return r;
}

__device__ __forceinline__ bf16x8 ldfrag(const u16* p) {
    return __builtin_bit_cast(bf16x8, *(const u16x8*)p);
}

__device__ __forceinline__ void async_cp16(const void* g, void* l) {
    __builtin_amdgcn_global_load_lds(
        (const __attribute__((address_space(1))) unsigned int*)g,
        (__attribute__((address_space(3))) unsigned int*)l, 16, 0, 0);
}

__device__ __forceinline__ uint2 pack4(float a, float b, float c, float d) {
    uint2 w;
    w.x = (u32)f2bf(a) | ((u32)f2bf(b) << 16);
    w.y = (u32)f2bf(c) | ((u32)f2bf(d) << 16);
    return w;
}

__device__ __forceinline__ f32x4 mfma32(bf16x8 a, bf16x8 b, f32x4 c) {
    return __builtin_amdgcn_mfma_f32_16x16x32_bf16(a, b, c, 0, 0, 0);
}

// ---------------- conversion kernels ----------------

__global__ void cvt_x(const float* __restrict__ x, u16* __restrict__ xb, int n4) {
    int i = blockIdx.x * blockDim.x + threadIdx.x;
    if (i < n4) {
        float4 v = ((const float4*)x)[i];
        ushort4 o;
        o.x = f2bf(v.x); o.y = f2bf(v.y); o.z = f2bf(v.z); o.w = f2bf(v.w);
        ((ushort4*)xb)[i] = o;
    }
}

// 4 weight transposes fused into one z-indexed launch (same body as the
// verified transp; block-uniform pointer select)
__global__ __launch_bounds__(1024)
void transp4(const float* __restrict__ s0, const float* __restrict__ s1,
             const float* __restrict__ s2, const float* __restrict__ s3,
             u16* __restrict__ d0, u16* __restrict__ d1,
             u16* __restrict__ d2, u16* __restrict__ d3) {
    __shared__ float t[32][33];
    const float* src;
    u16* dst;
    int z = blockIdx.z;
    if (z == 0)      { src = s0; dst = d0; }
    else if (z == 1) { src = s1; dst = d1; }
    else if (z == 2) { src = s2; dst = d2; }
    else             { src = s3; dst = d3; }
    int bx = blockIdx.x * 32, by = blockIdx.y * 32;
    t[threadIdx.y][threadIdx.x] = src[(by + threadIdx.y) * 1024 + bx + threadIdx.x];
    __syncthreads();
    dst[(bx + threadIdx.y) * 1024 + by + threadIdx.x] = f2bf(t[threadIdx.x][threadIdx.y]);
}

__global__ void mkbias(const float* __restrict__ bq, const float* __restrict__ bk,
                       const float* __restrict__ bv, float* __restrict__ bqkv) {
    int i = blockIdx.x * blockDim.x + threadIdx.x;
    if (i < 3072) bqkv[i] = (i < 1024) ? bq[i] : (i < 2048 ? bk[i - 1024] : bv[i - 2048]);
}

// ---------------- GEMM body: C[M,N] = A[M,K] * Bt[N,K]^T + bias ----------------
// r1/r5-verified structure: BK=64, XOR-swizzled unpadded LDS, 32
// MFMA/barrier-pair, 128x128 tile, 256 threads.

template <int EPI>
__device__ __forceinline__
void gemm_body(const u16* __restrict__ A, const u16* __restrict__ Bt,
               const float* __restrict__ bias,
               u16* __restrict__ Qb, u16* __restrict__ Kb, u16* __restrict__ Vt,
               float* __restrict__ outf,
               u16* Asm, u16* Bsm, int tileM, int tileN) {
    int tid = threadIdx.x;
    int wave = tid >> 6, lane = tid & 63;
    int lr = lane & 15, lq = lane >> 4;
    int wrow = (wave >> 1) * 64, wcol = (wave & 1) * 64;

    f32x4 acc[4][4];
    for (int i = 0; i < 4; i++)
        for (int j = 0; j < 4; j++)
            acc[i][j] = (f32x4){0.f, 0.f, 0.f, 0.f};

    int srow = tid >> 3;
    int sg = (tid & 7) ^ (srow & 7);
    const u16* ga = A + (tileM + srow) * 1024 + sg * 8;
    const u16* gb = Bt + (tileN + srow) * 1024 + sg * 8;
    u16* la = &Asm[tid * 8];
    u16* lb = &Bsm[tid * 8];

    int sw0 = ((lq ^ (lr & 7)) << 3);
    int sw1 = (((4 + lq) ^ (lr & 7)) << 3);

    for (int k0 = 0; k0 < 1024; k0 += 64) {
        for (int rnd = 0; rnd < 4; rnd++) {
            async_cp16(ga + k0 + rnd * 32 * 1024, la + rnd * 2048);
            async_cp16(gb + k0 + rnd * 32 * 1024, lb + rnd * 2048);
        }
        __syncthreads();
        for (int ko = 0; ko < 2; ko++) {
            int sw = ko ? sw1 : sw0;
            bf16x8 af[4], bfr[4];
            for (int mt = 0; mt < 4; mt++) af[mt] = ldfrag(&Asm[(wrow + mt * 16 + lr) * 64 + sw]);
            for (int nt = 0; nt < 4; nt++) bfr[nt] = ldfrag(&Bsm[(wcol + nt * 16 + lr) * 64 + sw]);
            for (int mt = 0; mt < 4; mt++)
                for (int nt = 0; nt < 4; nt++) {
                    if (EPI == 1)
                        acc[mt][nt] = __builtin_amdgcn_mfma_f32_16x16x32_bf16(af[mt], bfr[nt], acc[mt][nt], 0, 0, 0);
                    else
                        acc[mt][nt] = __builtin_amdgcn_mfma_f32_16x16x32_bf16(bfr[nt], af[mt], acc[mt][nt], 0, 0, 0);
                }
        }
        __syncthreads();
    }

    if (EPI == 0) {
        for (int mt = 0; mt < 4; mt++) {
            int m = tileM + wrow + mt * 16 + lr;
            int b = m >> 11, s = m & 2047;
            for (int nt = 0; nt < 4; nt++) {
                int n0 = tileN + wcol + nt * 16 + lq * 4;   // [0,2048)
                float4 bn = *(const float4*)&bias[n0];
                int which = n0 >> 10, d = n0 & 1023, h = d >> 6, dh = d & 63;
                u16* dst = (which ? Kb : Qb) + ((b * 16 + h) * 2048 + s) * 64 + dh;
                f32x4 v = acc[mt][nt];
                uint2 w;
                if (which == 0)
                    w = pack4((v[0] + bn.x) * QSCALE, (v[1] + bn.y) * QSCALE,
                              (v[2] + bn.z) * QSCALE, (v[3] + bn.w) * QSCALE);
                else
                    w = pack4(v[0] + bn.x, v[1] + bn.y, v[2] + bn.z, v[3] + bn.w);
                *(uint2*)dst = w;
            }
        }
    } else if (EPI == 1) {
        for (int nt = 0; nt < 4; nt++) {
            int n0 = tileN + wcol + nt * 16 + lr;           // [0,1024) V-local
            float bn = bias[n0];                            // caller passed bias+2048
            int h = n0 >> 6, dh = n0 & 63;
            for (int mt = 0; mt < 4; mt++) {
                int m0 = tileM + wrow + mt * 16 + lq * 4;
                int b = m0 >> 11, s = m0 & 2047;
                f32x4 v = acc[mt][nt];
                uint2 w = pack4(v[0] + bn, v[1] + bn, v[2] + bn, v[3] + bn);
                *(uint2*)(Vt + ((b * 16 + h) * 64 + dh) * 2048 + s) = w;
            }
        }
    } else {
        for (int mt = 0; mt < 4; mt++) {
            int m = tileM + wrow + mt * 16 + lr;
            for (int nt = 0; nt < 4; nt++) {
                int n0 = tileN + wcol + nt * 16 + lq * 4;
                float4 bn = *(const float4*)&bias[n0];
                f32x4 v = acc[mt][nt];
                float4 st = {v[0] + bn.x, v[1] + bn.y, v[2] + bn.z, v[3] + bn.w};
                *(float4*)&outf[m * 1024 + n0] = st;
            }
        }
    }
}

// Merged Q/K + V projection: grid (24,64). bx<16 -> QK path (N=2048 over Wq|Wk),
// bx>=16 -> V path (N=1024 over Wv). XCD-chunk swizzle (bijective, 1536=8x192).
// launch_bounds (256,4): cap VGPR at 128 -> >=4 blocks/CU resident.
__global__ __launch_bounds__(256, 4)
void gemmqkv(const u16* __restrict__ A, const u16* __restrict__ Wt,
             const float* __restrict__ bqkv,
             u16* __restrict__ Qb, u16* __restrict__ Kb, u16* __restrict__ Vtb) {
    __shared__ u16 Asm[128 * 64];
    __shared__ u16 Bsm[128 * 64];
    int lin = blockIdx.x + 24 * blockIdx.y;
    int nl = (lin & 7) * 192 + (lin >> 3);
    int bx = nl % 24, by = nl / 24;
    if (bx < 16)
        gemm_body<0>(A, Wt, bqkv, Qb, Kb, nullptr, nullptr,
                     Asm, Bsm, by * 128, bx * 128);
    else
        gemm_body<1>(A, Wt + 2048 * 1024, bqkv + 2048, nullptr, nullptr, Vtb, nullptr,
                     Asm, Bsm, by * 128, (bx - 16) * 128);
}

// Output projection
__global__ __launch_bounds__(256, 4)
void gemmo(const u16* __restrict__ A, const u16* __restrict__ Wot,
           const float* __restrict__ bo, float* __restrict__ outf) {
    __shared__ u16 Asm[128 * 64];
    __shared__ u16 Bsm[128 * 64];
    gemm_body<2>(A, Wot, bo, nullptr, nullptr, nullptr, outf,
                 Asm, Bsm, blockIdx.y * 128, blockIdx.x * 128);
}

// ---------------- flash attention ----------------
// This round: occupancy experiment. Body = r1-verified math (s=0..1, 32 q/wave,
// 128 q/block -> grid 1024 = 4 blocks/CU = 4 waves/SIMD) + the r5 XCD-chunk
// swizzle adapted to chunk=128 (each XCD still owns exactly 8 whole heads, so
// the FETCH mechanism is preserved; only L2-local re-reads double).
// launch_bounds (256,4): r1 body measured 68 VGPR, 4 blocks fit (LDS 128KB).
__global__ __launch_bounds__(256, 4)
void attn(const u16* __restrict__ Qb, const u16* __restrict__ Kb,
          const u16* __restrict__ Vt, u16* __restrict__ Ob) {
    __shared__ u16 Ksm[2][64 * 64];
    __shared__ u16 Vsm[2][64 * 64];
    int tid = threadIdx.x;
    int wave = tid >> 6, lane = tid & 63;
    int lr = lane & 15, lq = lane >> 4;

    // grid (16,64): lin in dispatch order; remap so lin%8 (the XCD under
    // round-robin) selects a contiguous 128-block chunk (= 8 whole heads)
    int lin = blockIdx.x + (blockIdx.y << 4);
    int nl = ((lin & 7) << 7) + (lin >> 3);
    int qx = nl & 15, bh = nl >> 4;
    int b = bh >> 4, h = bh & 15;
    int qbase = qx * 128 + wave * 32;

    const u16* Qh = Qb + bh * 2048 * 64;
    const u16* Kh = Kb + bh * 2048 * 64;
    const u16* Vh = Vt + bh * 64 * 2048;

    bf16x8 qf[2][2];
#pragma unroll
    for (int s = 0; s < 2; s++)
#pragma unroll
        for (int hf = 0; hf < 2; hf++)
            qf[s][hf] = ldfrag(Qh + (qbase + s * 16 + lr) * 64 + hf * 32 + lq * 8);

    f32x4 o[2][4];
    float lacc[2] = {0.f, 0.f};
#pragma unroll
    for (int s = 0; s < 2; s++)
#pragma unroll
        for (int dt = 0; dt < 4; dt++) o[s][dt] = (f32x4){0.f, 0.f, 0.f, 0.f};

    // QK^T A-operand read offsets (key-permuted rows, g()-swizzled groups)
    int row0 = ((lr & 12) << 1) | (lr & 3);        // pi(lr): {0-3,8-11,16-19,24-27}
    int gg = (lr & 3) | (((lr >> 2) & 1) << 2);    // g(row0) == g(row0+4), kg2-invariant
    int kofs = row0 * 64 + ((lq ^ gg) << 3);       // u16 units; +256 = +4 rows; ^32 = d-half
    // PV A-operand (V^T): b128 covering keys kg2*32 + lq*8 .. +7 at row dt*16+lr
    int vofs0 = (lq ^ (lr & 7)) << 3;              // kg2=0; kg2=1 is ^32

    int sr = tid >> 3, sg = tid & 7;
    int gK = (sg ^ ((sr & 3) | (((sr >> 3) & 1) << 2))) << 3;  // inverse-swz source for K
    int gV = (sg ^ (sr & 7)) << 3;                             // V keeps row&7 swizzle
    const u16* gk = Kh + sr * 64 + gK;
    const u16* gv = Vh + sr * 2048 + gV;

    // prologue: stage tile 0 into buffer 0
    async_cp16(gk, &Ksm[0][tid * 8]);
    async_cp16(gk + 32 * 64, &Ksm[0][tid * 8 + 32 * 64]);
    async_cp16(gv, &Vsm[0][tid * 8]);
    async_cp16(gv + 32 * 2048, &Vsm[0][tid * 8 + 32 * 64]);

    for (int it = 0; it < 32; ++it) {
        int p = it & 1;
        __syncthreads();   // tile p DMA drained; all reads of buffer p^1 done

        if (it < 31) {     // stage next tile into p^1, overlapped with this iter
            gk += 64 * 64; gv += 64;
            async_cp16(gk, &Ksm[p ^ 1][tid * 8]);
            async_cp16(gk + 32 * 64, &Ksm[p ^ 1][tid * 8 + 32 * 64]);
            async_cp16(gv, &Vsm[p ^ 1][tid * 8]);
            async_cp16(gv + 32 * 2048, &Vsm[p ^ 1][tid * 8 + 32 * 64]);
        }

        const u16* Kp = Ksm[p];
        const u16* Vp = Vsm[p];

        // S^T = K Q^T with permuted key rows: lane (lq,lr) gets scores for
        // query lr, keys kg2*32 + lq*8 + {0..7} (sa: +0..3, sb: +4..7)
        bf16x8 pb[2][2];
#pragma unroll
        for (int kg2 = 0; kg2 < 2; kg2++) {
            int ka = kofs + kg2 * 2048;
            bf16x8 kA0 = ldfrag(Kp + ka);
            bf16x8 kA1 = ldfrag(Kp + (ka ^ 32));
            bf16x8 kB0 = ldfrag(Kp + ka + 256);
            bf16x8 kB1 = ldfrag(Kp + ((ka + 256) ^ 32));
#pragma unroll
            for (int s = 0; s < 2; s++) {
                f32x4 sa = (f32x4){0.f, 0.f, 0.f, 0.f};
                f32x4 sb = (f32x4){0.f, 0.f, 0.f, 0.f};
                sa = mfma32(kA0, qf[s][0], sa);
                sa = mfma32(kA1, qf[s][1], sa);
                sb = mfma32(kB0, qf[s][0], sb);
                sb = mfma32(kB1, qf[s][1], sb);
                float e0 = __builtin_amdgcn_exp2f(sa[0]);
                float e1 = __builtin_amdgcn_exp2f(sa[1]);
                float e2 = __builtin_amdgcn_exp2f(sa[2]);
                float e3 = __builtin_amdgcn_exp2f(sa[3]);
                float e4 = __builtin_amdgcn_exp2f(sb[0]);
                float e5 = __builtin_amdgcn_exp2f(sb[1]);
                float e6 = __builtin_amdgcn_exp2f(sb[2]);
                float e7 = __builtin_amdgcn_exp2f(sb[3]);
                lacc[s] += ((e0 + e1) + (e2 + e3)) + ((e4 + e5) + (e6 + e7));
                u32x4 pw = {cvtpk(e0, e1), cvtpk(e2, e3), cvtpk(e4, e5), cvtpk(e6, e7)};
                pb[kg2][s] = __builtin_bit_cast(bf16x8, pw);
            }
        }

        // O^T += V^T P^T, full-rate K=32: pb is already the B-operand
#pragma unroll
        for (int dt = 0; dt < 4; dt++) {
            int rb = (dt * 16 + lr) * 64;
            bf16x8 v0 = ldfrag(Vp + rb + vofs0);
            bf16x8 v1 = ldfrag(Vp + rb + (vofs0 ^ 32));
#pragma unroll
            for (int s = 0; s < 2; s++) {
                o[s][dt] = mfma32(v0, pb[0][s], o[s][dt]);
                o[s][dt] = mfma32(v1, pb[1][s], o[s][dt]);
            }
        }
    }

    // reduce l over the 4 lq lanes of each query column
#pragma unroll
    for (int s = 0; s < 2; s++) {
        lacc[s] += __shfl_xor(lacc[s], 16);
        lacc[s] += __shfl_xor(lacc[s], 32);
    }

    // O^T C-layout: col = query = lr, rows = d = dt*16 + lq*4 + r
#pragma unroll
    for (int s = 0; s < 2; s++) {
        float linv = 1.0f / lacc[s];
        int q = qbase + s * 16 + lr;
        u16* obase = Ob + (b * 2048 + q) * 1024 + h * 64 + lq * 4;
#pragma unroll
        for (int dt = 0; dt < 4; dt++) {
            uint2 w = pack4(o[s][dt][0] * linv, o[s][dt][1] * linv,
                            o[s][dt][2] * linv, o[s][dt][3] * linv);
            *(uint2*)(obase + dt * 16) = w;
        }
    }
}

// ---------------- launch ----------------

extern "C" void kernel_launch(void* const* d_in, const int* in_sizes, int n_in,
                              void* d_out, int out_size, void* d_ws, size_t ws_size,
                              hipStream_t stream) {
    const float* x  = (const float*)d_in[0];
    const float* Wq = (const float*)d_in[1];
    const float* bq = (const float*)d_in[2];
    const float* Wk = (const float*)d_in[3];
    const float* bk = (const float*)d_in[4];
    const float* Wv = (const float*)d_in[5];
    const float* bv = (const float*)d_in[6];
    const float* Wo = (const float*)d_in[7];
    const float* bo = (const float*)d_in[8];
    float* out = (float*)d_out;

    char* ws = (char*)d_ws;
    u16* xb    = (u16*)ws;                    // 16 MiB bf16 x; reused as attention output
    u16* Wt    = (u16*)(ws + (16u << 20));    // 6 MiB (Wq|Wk|Wv transposed, bf16)
    u16* Wot   = (u16*)(ws + (22u << 20));    // 2 MiB
    float* bqkv = (float*)(ws + (24u << 20)); // 12 KiB
    u16* Vtb   = (u16*)(ws + (25u << 20));    // 16 MiB [B,H,64,S]
    u16* Qb    = (u16*)d_out;                 // 16 MiB [B,H,S,64]  (d_out scratch)
    u16* Kb    = Qb + 4 * 16 * 2048 * 64;     // 16 MiB [B,H,S,64]  (d_out scratch)

    cvt_x<<<8192, 256, 0, stream>>>(x, xb, 8192 * 1024 / 4);
    dim3 tb(32, 32);
    transp4<<<dim3(32, 32, 4), tb, 0, stream>>>(Wq, Wk, Wv, Wo,
                                                Wt, Wt + 1024 * 1024,
                                                Wt + 2 * 1024 * 1024, Wot);
    mkbias<<<12, 256, 0, stream>>>(bq, bk, bv, bqkv);

    gemmqkv<<<dim3(24, 64), 256, 0, stream>>>(xb, Wt, bqkv, Qb, Kb, Vtb);
    attn<<<dim3(16, 64), 256, 0, stream>>>(Qb, Kb, Vtb, xb);
    gemmo<<<dim3(8, 64), 256, 0, stream>>>(xb, Wot, bo, out);
}

// Round 9
// 269.161 us; speedup vs baseline: 1.1047x; 1.1047x over previous
//
#include <hip/hip_runtime.h>

typedef unsigned short u16;
typedef unsigned int u32;
typedef unsigned short u16x8 __attribute__((ext_vector_type(8)));
typedef unsigned int u32x4 __attribute__((ext_vector_type(4)));
typedef __bf16 bf16x8 __attribute__((ext_vector_type(8)));
typedef float f32x4 __attribute__((ext_vector_type(4)));

#define QSCALE 0.18033688011112042f  /* 0.125 * log2(e) */

__device__ __forceinline__ u16 f2bf(float f) {
    unsigned u = __float_as_uint(f);
    u += 0x7fffu + ((u >> 16) & 1u);
    return (u16)(u >> 16);
}

// single-instruction packed f32x2 -> bf16x2 (RTNE), used in the attn hot loop
__device__ __forceinline__ u32 cvtpk(float lo, float hi) {
    u32 r;
    asm("v_cvt_pk_bf16_f32 %0, %1, %2" : "=v"(r) : "v"(lo), "v"(hi));
    return r;
}

__device__ __forceinline__ bf16x8 ldfrag(const u16* p) {
    return __builtin_bit_cast(bf16x8, *(const u16x8*)p);
}

__device__ __forceinline__ void async_cp16(const void* g, void* l) {
    __builtin_amdgcn_global_load_lds(
        (const __attribute__((address_space(1))) unsigned int*)g,
        (__attribute__((address_space(3))) unsigned int*)l, 16, 0, 0);
}

__device__ __forceinline__ uint2 pack4(float a, float b, float c, float d) {
    uint2 w;
    w.x = (u32)f2bf(a) | ((u32)f2bf(b) << 16);
    w.y = (u32)f2bf(c) | ((u32)f2bf(d) << 16);
    return w;
}

__device__ __forceinline__ f32x4 mfma32(bf16x8 a, bf16x8 b, f32x4 c) {
    return __builtin_amdgcn_mfma_f32_16x16x32_bf16(a, b, c, 0, 0, 0);
}

// ---------------- conversion kernels ----------------

__global__ void cvt_x(const float* __restrict__ x, u16* __restrict__ xb, int n4) {
    int i = blockIdx.x * blockDim.x + threadIdx.x;
    if (i < n4) {
        float4 v = ((const float4*)x)[i];
        ushort4 o;
        o.x = f2bf(v.x); o.y = f2bf(v.y); o.z = f2bf(v.z); o.w = f2bf(v.w);
        ((ushort4*)xb)[i] = o;
    }
}

// 4 weight transposes fused into one z-indexed launch
__global__ __launch_bounds__(1024)
void transp4(const float* __restrict__ s0, const float* __restrict__ s1,
             const float* __restrict__ s2, const float* __restrict__ s3,
             u16* __restrict__ d0, u16* __restrict__ d1,
             u16* __restrict__ d2, u16* __restrict__ d3) {
    __shared__ float t[32][33];
    const float* src;
    u16* dst;
    int z = blockIdx.z;
    if (z == 0)      { src = s0; dst = d0; }
    else if (z == 1) { src = s1; dst = d1; }
    else if (z == 2) { src = s2; dst = d2; }
    else             { src = s3; dst = d3; }
    int bx = blockIdx.x * 32, by = blockIdx.y * 32;
    t[threadIdx.y][threadIdx.x] = src[(by + threadIdx.y) * 1024 + bx + threadIdx.x];
    __syncthreads();
    dst[(bx + threadIdx.y) * 1024 + by + threadIdx.x] = f2bf(t[threadIdx.x][threadIdx.y]);
}

__global__ void mkbias(const float* __restrict__ bq, const float* __restrict__ bk,
                       const float* __restrict__ bv, float* __restrict__ bqkv) {
    int i = blockIdx.x * blockDim.x + threadIdx.x;
    if (i < 3072) bqkv[i] = (i < 1024) ? bq[i] : (i < 2048 ? bk[i - 1024] : bv[i - 2048]);
}

// ---------------- GEMM body: C[M,N] = A[M,K] * Bt[N,K]^T + bias ----------------
// r1/r5-verified structure: BK=64, XOR-swizzled unpadded LDS, 32
// MFMA/barrier-pair, 128x128 tile, 256 threads. NO launch_bounds min-wave cap
// (r8 measured: (256,4) cost ~11 us aggregate -> VGPR cap hurt).

template <int EPI>
__device__ __forceinline__
void gemm_body(const u16* __restrict__ A, const u16* __restrict__ Bt,
               const float* __restrict__ bias,
               u16* __restrict__ Qb, u16* __restrict__ Kb, u16* __restrict__ Vt,
               float* __restrict__ outf,
               u16* Asm, u16* Bsm, int tileM, int tileN) {
    int tid = threadIdx.x;
    int wave = tid >> 6, lane = tid & 63;
    int lr = lane & 15, lq = lane >> 4;
    int wrow = (wave >> 1) * 64, wcol = (wave & 1) * 64;

    f32x4 acc[4][4];
    for (int i = 0; i < 4; i++)
        for (int j = 0; j < 4; j++)
            acc[i][j] = (f32x4){0.f, 0.f, 0.f, 0.f};

    int srow = tid >> 3;
    int sg = (tid & 7) ^ (srow & 7);
    const u16* ga = A + (tileM + srow) * 1024 + sg * 8;
    const u16* gb = Bt + (tileN + srow) * 1024 + sg * 8;
    u16* la = &Asm[tid * 8];
    u16* lb = &Bsm[tid * 8];

    int sw0 = ((lq ^ (lr & 7)) << 3);
    int sw1 = (((4 + lq) ^ (lr & 7)) << 3);

    for (int k0 = 0; k0 < 1024; k0 += 64) {
        for (int rnd = 0; rnd < 4; rnd++) {
            async_cp16(ga + k0 + rnd * 32 * 1024, la + rnd * 2048);
            async_cp16(gb + k0 + rnd * 32 * 1024, lb + rnd * 2048);
        }
        __syncthreads();
        for (int ko = 0; ko < 2; ko++) {
            int sw = ko ? sw1 : sw0;
            bf16x8 af[4], bfr[4];
            for (int mt = 0; mt < 4; mt++) af[mt] = ldfrag(&Asm[(wrow + mt * 16 + lr) * 64 + sw]);
            for (int nt = 0; nt < 4; nt++) bfr[nt] = ldfrag(&Bsm[(wcol + nt * 16 + lr) * 64 + sw]);
            for (int mt = 0; mt < 4; mt++)
                for (int nt = 0; nt < 4; nt++) {
                    if (EPI == 1)
                        acc[mt][nt] = __builtin_amdgcn_mfma_f32_16x16x32_bf16(af[mt], bfr[nt], acc[mt][nt], 0, 0, 0);
                    else
                        acc[mt][nt] = __builtin_amdgcn_mfma_f32_16x16x32_bf16(bfr[nt], af[mt], acc[mt][nt], 0, 0, 0);
                }
        }
        __syncthreads();
    }

    if (EPI == 0) {
        for (int mt = 0; mt < 4; mt++) {
            int m = tileM + wrow + mt * 16 + lr;
            int b = m >> 11, s = m & 2047;
            for (int nt = 0; nt < 4; nt++) {
                int n0 = tileN + wcol + nt * 16 + lq * 4;   // [0,2048)
                float4 bn = *(const float4*)&bias[n0];
                int which = n0 >> 10, d = n0 & 1023, h = d >> 6, dh = d & 63;
                u16* dst = (which ? Kb : Qb) + ((b * 16 + h) * 2048 + s) * 64 + dh;
                f32x4 v = acc[mt][nt];
                uint2 w;
                if (which == 0)
                    w = pack4((v[0] + bn.x) * QSCALE, (v[1] + bn.y) * QSCALE,
                              (v[2] + bn.z) * QSCALE, (v[3] + bn.w) * QSCALE);
                else
                    w = pack4(v[0] + bn.x, v[1] + bn.y, v[2] + bn.z, v[3] + bn.w);
                *(uint2*)dst = w;
            }
        }
    } else if (EPI == 1) {
        for (int nt = 0; nt < 4; nt++) {
            int n0 = tileN + wcol + nt * 16 + lr;           // [0,1024) V-local
            float bn = bias[n0];                            // caller passed bias+2048
            int h = n0 >> 6, dh = n0 & 63;
            for (int mt = 0; mt < 4; mt++) {
                int m0 = tileM + wrow + mt * 16 + lq * 4;
                int b = m0 >> 11, s = m0 & 2047;
                f32x4 v = acc[mt][nt];
                uint2 w = pack4(v[0] + bn, v[1] + bn, v[2] + bn, v[3] + bn);
                *(uint2*)(Vt + ((b * 16 + h) * 64 + dh) * 2048 + s) = w;
            }
        }
    } else {
        for (int mt = 0; mt < 4; mt++) {
            int m = tileM + wrow + mt * 16 + lr;
            for (int nt = 0; nt < 4; nt++) {
                int n0 = tileN + wcol + nt * 16 + lq * 4;
                float4 bn = *(const float4*)&bias[n0];
                f32x4 v = acc[mt][nt];
                float4 st = {v[0] + bn.x, v[1] + bn.y, v[2] + bn.z, v[3] + bn.w};
                *(float4*)&outf[m * 1024 + n0] = st;
            }
        }
    }
}

// Merged Q/K + V projection: grid (24,64). bx<16 -> QK path (N=2048 over Wq|Wk),
// bx>=16 -> V path (N=1024 over Wv). XCD-chunk swizzle (bijective, 1536=8x192).
__global__ __launch_bounds__(256)
void gemmqkv(const u16* __restrict__ A, const u16* __restrict__ Wt,
             const float* __restrict__ bqkv,
             u16* __restrict__ Qb, u16* __restrict__ Kb, u16* __restrict__ Vtb) {
    __shared__ u16 Asm[128 * 64];
    __shared__ u16 Bsm[128 * 64];
    int lin = blockIdx.x + 24 * blockIdx.y;
    int nl = (lin & 7) * 192 + (lin >> 3);
    int bx = nl % 24, by = nl / 24;
    if (bx < 16)
        gemm_body<0>(A, Wt, bqkv, Qb, Kb, nullptr, nullptr,
                     Asm, Bsm, by * 128, bx * 128);
    else
        gemm_body<1>(A, Wt + 2048 * 1024, bqkv + 2048, nullptr, nullptr, Vtb, nullptr,
                     Asm, Bsm, by * 128, (bx - 16) * 128);
}

// Output projection
__global__ __launch_bounds__(256)
void gemmo(const u16* __restrict__ A, const u16* __restrict__ Wot,
           const float* __restrict__ bo, float* __restrict__ outf) {
    __shared__ u16 Asm[128 * 64];
    __shared__ u16 Bsm[128 * 64];
    gemm_body<2>(A, Wot, bo, nullptr, nullptr, nullptr, outf,
                 Asm, Bsm, blockIdx.y * 128, blockIdx.x * 128);
}

// ---------------- flash attention ----------------
// r5-verified s=4 body (256 q/block, key-permuted QK^T -> P is directly the
// K=32 MFMA B-operand, conflict-free b128 K/V reads, cvt_pk pack, XCD-chunk
// swizzle). NEW this round: TWO K/V tiles per barrier (KVBLK=128 via two
// ping-pong buffer PAIRS) -- halves the per-barrier stall count (r8 proved
// occupancy doesn't hide it; amortization is the lever that measured). The
// per-tile inner body, addressing, and swizzles are byte-identical; only the
// buffer index and pointer strides changed. LDS 64KB -> still 2 blocks/CU.
__global__ __launch_bounds__(256, 2)
void attn(const u16* __restrict__ Qb, const u16* __restrict__ Kb,
          const u16* __restrict__ Vt, u16* __restrict__ Ob) {
    __shared__ u16 Ksm[4][64 * 64];
    __shared__ u16 Vsm[4][64 * 64];
    int tid = threadIdx.x;
    int wave = tid >> 6, lane = tid & 63;
    int lr = lane & 15, lq = lane >> 4;

    // grid (8,64): remap so lin%8 (the XCD under round-robin) selects a
    // contiguous 64-block chunk (= 8 whole heads per XCD)
    int lin = blockIdx.x + (blockIdx.y << 3);
    int nl = ((lin & 7) << 6) + (lin >> 3);
    int qx = nl & 7, bh = nl >> 3;
    int b = bh >> 4, h = bh & 15;
    int qbase = qx * 256 + wave * 64;

    const u16* Qh = Qb + bh * 2048 * 64;
    const u16* Kh = Kb + bh * 2048 * 64;
    const u16* Vh = Vt + bh * 64 * 2048;

    bf16x8 qf[4][2];
#pragma unroll
    for (int s = 0; s < 4; s++)
#pragma unroll
        for (int hf = 0; hf < 2; hf++)
            qf[s][hf] = ldfrag(Qh + (qbase + s * 16 + lr) * 64 + hf * 32 + lq * 8);

    f32x4 o[4][4];
    float lacc[4] = {0.f, 0.f, 0.f, 0.f};
#pragma unroll
    for (int s = 0; s < 4; s++)
#pragma unroll
        for (int dt = 0; dt < 4; dt++) o[s][dt] = (f32x4){0.f, 0.f, 0.f, 0.f};

    // QK^T A-operand read offsets (key-permuted rows, g()-swizzled groups)
    int row0 = ((lr & 12) << 1) | (lr & 3);        // pi(lr): {0-3,8-11,16-19,24-27}
    int gg = (lr & 3) | (((lr >> 2) & 1) << 2);    // g(row0) == g(row0+4), kg2-invariant
    int kofs = row0 * 64 + ((lq ^ gg) << 3);       // u16 units; +256 = +4 rows; ^32 = d-half
    // PV A-operand (V^T): b128 covering keys kg2*32 + lq*8 .. +7 at row dt*16+lr
    int vofs0 = (lq ^ (lr & 7)) << 3;              // kg2=0; kg2=1 is ^32

    int sr = tid >> 3, sg = tid & 7;
    int gK = (sg ^ ((sr & 3) | (((sr >> 3) & 1) << 2))) << 3;  // inverse-swz source for K
    int gV = (sg ^ (sr & 7)) << 3;                             // V keeps row&7 swizzle
    const u16* gk = Kh + sr * 64 + gK;
    const u16* gv = Vh + sr * 2048 + gV;

    // prologue: stage tiles 0,1 into buffers 0,1 (pair 0)
#pragma unroll
    for (int tt = 0; tt < 2; ++tt) {
        async_cp16(gk + tt * 4096, &Ksm[tt][tid * 8]);
        async_cp16(gk + tt * 4096 + 32 * 64, &Ksm[tt][tid * 8 + 32 * 64]);
        async_cp16(gv + tt * 64, &Vsm[tt][tid * 8]);
        async_cp16(gv + tt * 64 + 32 * 2048, &Vsm[tt][tid * 8 + 32 * 64]);
    }

    for (int it = 0; it < 16; ++it) {
        int p = (it & 1) * 2;      // current buffer pair base (0 or 2)
        __syncthreads();           // pair p DMA drained; reads of pair p^2 done

        if (it < 15) {             // stage next 2 tiles into the other pair
            gk += 2 * 4096; gv += 2 * 64;
            int q = p ^ 2;
#pragma unroll
            for (int tt = 0; tt < 2; ++tt) {
                async_cp16(gk + tt * 4096, &Ksm[q + tt][tid * 8]);
                async_cp16(gk + tt * 4096 + 32 * 64, &Ksm[q + tt][tid * 8 + 32 * 64]);
                async_cp16(gv + tt * 64, &Vsm[q + tt][tid * 8]);
                async_cp16(gv + tt * 64 + 32 * 2048, &Vsm[q + tt][tid * 8 + 32 * 64]);
            }
        }

        // two tiles per barrier: identical per-tile body
#pragma unroll
        for (int half = 0; half < 2; ++half) {
            const u16* Kp = Ksm[p + half];
            const u16* Vp = Vsm[p + half];

            // S^T = K Q^T with permuted key rows: lane (lq,lr) gets scores for
            // query lr, keys kg2*32 + lq*8 + {0..7} (sa: +0..3, sb: +4..7)
            bf16x8 pb[2][4];
#pragma unroll
            for (int kg2 = 0; kg2 < 2; kg2++) {
                int ka = kofs + kg2 * 2048;
                bf16x8 kA0 = ldfrag(Kp + ka);
                bf16x8 kA1 = ldfrag(Kp + (ka ^ 32));
                bf16x8 kB0 = ldfrag(Kp + ka + 256);
                bf16x8 kB1 = ldfrag(Kp + ((ka + 256) ^ 32));
#pragma unroll
                for (int s = 0; s < 4; s++) {
                    f32x4 sa = (f32x4){0.f, 0.f, 0.f, 0.f};
                    f32x4 sb = (f32x4){0.f, 0.f, 0.f, 0.f};
                    sa = mfma32(kA0, qf[s][0], sa);
                    sa = mfma32(kA1, qf[s][1], sa);
                    sb = mfma32(kB0, qf[s][0], sb);
                    sb = mfma32(kB1, qf[s][1], sb);
                    float e0 = __builtin_amdgcn_exp2f(sa[0]);
                    float e1 = __builtin_amdgcn_exp2f(sa[1]);
                    float e2 = __builtin_amdgcn_exp2f(sa[2]);
                    float e3 = __builtin_amdgcn_exp2f(sa[3]);
                    float e4 = __builtin_amdgcn_exp2f(sb[0]);
                    float e5 = __builtin_amdgcn_exp2f(sb[1]);
                    float e6 = __builtin_amdgcn_exp2f(sb[2]);
                    float e7 = __builtin_amdgcn_exp2f(sb[3]);
                    lacc[s] += ((e0 + e1) + (e2 + e3)) + ((e4 + e5) + (e6 + e7));
                    u32x4 pw = {cvtpk(e0, e1), cvtpk(e2, e3), cvtpk(e4, e5), cvtpk(e6, e7)};
                    pb[kg2][s] = __builtin_bit_cast(bf16x8, pw);
                }
            }

            // O^T += V^T P^T, full-rate K=32: pb is already the B-operand
#pragma unroll
            for (int dt = 0; dt < 4; dt++) {
                int rb = (dt * 16 + lr) * 64;
                bf16x8 v0 = ldfrag(Vp + rb + vofs0);
                bf16x8 v1 = ldfrag(Vp + rb + (vofs0 ^ 32));
#pragma unroll
                for (int s = 0; s < 4; s++) {
                    o[s][dt] = mfma32(v0, pb[0][s], o[s][dt]);
                    o[s][dt] = mfma32(v1, pb[1][s], o[s][dt]);
                }
            }
        }
    }

    // reduce l over the 4 lq lanes of each query column
#pragma unroll
    for (int s = 0; s < 4; s++) {
        lacc[s] += __shfl_xor(lacc[s], 16);
        lacc[s] += __shfl_xor(lacc[s], 32);
    }

    // O^T C-layout: col = query = lr, rows = d = dt*16 + lq*4 + r
#pragma unroll
    for (int s = 0; s < 4; s++) {
        float linv = 1.0f / lacc[s];
        int q = qbase + s * 16 + lr;
        u16* obase = Ob + (b * 2048 + q) * 1024 + h * 64 + lq * 4;
#pragma unroll
        for (int dt = 0; dt < 4; dt++) {
            uint2 w = pack4(o[s][dt][0] * linv, o[s][dt][1] * linv,
                            o[s][dt][2] * linv, o[s][dt][3] * linv);
            *(uint2*)(obase + dt * 16) = w;
        }
    }
}

// ---------------- launch ----------------

extern "C" void kernel_launch(void* const* d_in, const int* in_sizes, int n_in,
                              void* d_out, int out_size, void* d_ws, size_t ws_size,
                              hipStream_t stream) {
    const float* x  = (const float*)d_in[0];
    const float* Wq = (const float*)d_in[1];
    const float* bq = (const float*)d_in[2];
    const float* Wk = (const float*)d_in[3];
    const float* bk = (const float*)d_in[4];
    const float* Wv = (const float*)d_in[5];
    const float* bv = (const float*)d_in[6];
    const float* Wo = (const float*)d_in[7];
    const float* bo = (const float*)d_in[8];
    float* out = (float*)d_out;

    char* ws = (char*)d_ws;
    u16* xb    = (u16*)ws;                    // 16 MiB bf16 x; reused as attention output
    u16* Wt    = (u16*)(ws + (16u << 20));    // 6 MiB (Wq|Wk|Wv transposed, bf16)
    u16* Wot   = (u16*)(ws + (22u << 20));    // 2 MiB
    float* bqkv = (float*)(ws + (24u << 20)); // 12 KiB
    u16* Vtb   = (u16*)(ws + (25u << 20));    // 16 MiB [B,H,64,S]
    u16* Qb    = (u16*)d_out;                 // 16 MiB [B,H,S,64]  (d_out scratch)
    u16* Kb    = Qb + 4 * 16 * 2048 * 64;     // 16 MiB [B,H,S,64]  (d_out scratch)

    cvt_x<<<8192, 256, 0, stream>>>(x, xb, 8192 * 1024 / 4);
    dim3 tb(32, 32);
    transp4<<<dim3(32, 32, 4), tb, 0, stream>>>(Wq, Wk, Wv, Wo,
                                                Wt, Wt + 1024 * 1024,
                                                Wt + 2 * 1024 * 1024, Wot);
    mkbias<<<12, 256, 0, stream>>>(bq, bk, bv, bqkv);

    gemmqkv<<<dim3(24, 64), 256, 0, stream>>>(xb, Wt, bqkv, Qb, Kb, Vtb);
    attn<<<dim3(8, 64), 256, 0, stream>>>(Qb, Kb, Vtb, xb);
    gemmo<<<dim3(8, 64), 256, 0, stream>>>(xb, Wot, bo, out);
}